// Round 5
// baseline (151.029 us; speedup 1.0000x reference)
//
#include <hip/hip_runtime.h>
#include <hip/hip_bf16.h>

#define NROWS 8192
#define DDIM  256
#define INV_TEMP 20.0f   // 1/0.05

typedef __attribute__((ext_vector_type(8)))  short bf16x8;
typedef __attribute__((ext_vector_type(16))) float f32x16;

// ---------------------------------------------------------------------------
// Fragment-major layout (bf16 elements), used for BOTH qn and pn:
//   row r, elem e:  s=e>>4 (kstep), h=(e>>3)&1, j=e&7, cb=r>>5, c=r&31
//   elem offset = (((s*256 + cb)*2 + h)*32 + c)*8 + j
// One (cb, s) block = 512 elems = 1 KB, contiguous. An MFMA 32x32x16 fragment
// (A or B) is exactly: lane l reads 8 elems at block_base + l*8 -> one fully
// coalesced global_load_dwordx4 per fragment. No LDS, no barriers needed.
// ---------------------------------------------------------------------------

// ---------------------------------------------------------------------------
// Kernel 1: per-row L2-normalize q,p (fp32), write bf16 in fragment-major
// layout, fp32 diag, zero lse + counter. One wave/row, 4 rows/256-thr block.
// ---------------------------------------------------------------------------
__global__ __launch_bounds__(256) void norm_diag_kernel(
    const float* __restrict__ q, const float* __restrict__ p,
    unsigned short* __restrict__ qn, unsigned short* __restrict__ pn,
    float* __restrict__ diag, float* __restrict__ lse,
    unsigned int* __restrict__ counter)
{
    const int row  = blockIdx.x * 4 + (threadIdx.x >> 6);
    const int lane = threadIdx.x & 63;

    const float4 qv = ((const float4*)(q + (size_t)row * DDIM))[lane];
    const float4 pv = ((const float4*)(p + (size_t)row * DDIM))[lane];

    float sq = qv.x*qv.x + qv.y*qv.y + qv.z*qv.z + qv.w*qv.w;
    float sp = pv.x*pv.x + pv.y*pv.y + pv.z*pv.z + pv.w*pv.w;
    #pragma unroll
    for (int m = 1; m < 64; m <<= 1) {
        sq += __shfl_xor(sq, m);
        sp += __shfl_xor(sp, m);
    }
    const float qs = 1.0f / fmaxf(sqrtf(sq), 1e-8f);
    const float ps = 1.0f / fmaxf(sqrtf(sp), 1e-8f);

    const float qx = qv.x*qs, qy = qv.y*qs, qz = qv.z*qs, qw = qv.w*qs;
    const float px = pv.x*ps, py = pv.y*ps, pz = pv.z*ps, pw = pv.w*ps;

    float d = qx*px + qy*py + qz*pz + qw*pw;
    #pragma unroll
    for (int m = 1; m < 64; m <<= 1) d += __shfl_xor(d, m);
    if (lane == 0) {
        diag[row] = d * INV_TEMP;
        lse[row]  = 0.0f;              // ws re-poisoned every call
    }
    if (blockIdx.x == 0 && threadIdx.x == 0) *counter = 0u;

    union { unsigned short u16[4]; uint2 v; } uq, up;
    {
        __hip_bfloat16 b;
        b = __float2bfloat16(qx); uq.u16[0] = *(unsigned short*)&b;
        b = __float2bfloat16(qy); uq.u16[1] = *(unsigned short*)&b;
        b = __float2bfloat16(qz); uq.u16[2] = *(unsigned short*)&b;
        b = __float2bfloat16(qw); uq.u16[3] = *(unsigned short*)&b;
        b = __float2bfloat16(px); up.u16[0] = *(unsigned short*)&b;
        b = __float2bfloat16(py); up.u16[1] = *(unsigned short*)&b;
        b = __float2bfloat16(pz); up.u16[2] = *(unsigned short*)&b;
        b = __float2bfloat16(pw); up.u16[3] = *(unsigned short*)&b;
    }
    // lane's 4 elems: e0 = 4*lane -> s=lane>>2, h=(lane>>1)&1, jbyte=8*(lane&1)
    const int s = lane >> 2, h = (lane >> 1) & 1;
    const int cb = row >> 5, c = row & 31;
    const size_t dst = ((size_t)(s * 256 + cb) << 10) + (h << 9) + (c << 4)
                     + ((lane & 1) << 3);
    *(uint2*)((char*)qn + dst) = uq.v;
    *(uint2*)((char*)pn + dst) = up.v;
}

// ---------------------------------------------------------------------------
// Kernel 2: barrier-free fused GEMM + sum-exp + (last block) final loss.
// Block = 4 waves. Wave owns 64 rows as two 32x32x16 A-tiles held in 128
// VGPRs for the FULL K=256 (loaded once, coalesced). B fragments stream
// global->VGPR via a depth-4 rolling buffer (prefetch distance 8 MFMAs);
// compiler emits fine-grained vmcnt (never a vmcnt(0) drain). All 4 waves
// walk the same B addresses -> L1 reuse. No __syncthreads in main loop.
// MFMA 32x32x16 layouts: A lane: row=l&31, k=(l>>5)*8+j (fragment-major 1KB
// block); B identical with col=l&31. C/D: col=l&31,
// row=(reg&3)+8*(reg>>2)+4*(l>>5)  [m74/m101-verified].
// exp without max-subtraction: |sim|<=20.5 -> exp<=8e8, lse<4e12, fits fp32.
// ---------------------------------------------------------------------------
__global__ __launch_bounds__(256, 2) void simexp_kernel(
    const unsigned short* __restrict__ qn,
    const unsigned short* __restrict__ pn,
    float* __restrict__ lse, const float* __restrict__ diag,
    unsigned int* __restrict__ counter, float* __restrict__ out)
{
    __shared__ float wsum[4];
    __shared__ unsigned int is_last;

    const int tid  = threadIdx.x;
    const int lane = tid & 63;
    const int w    = tid >> 6;
    const int rowstart = blockIdx.y * 256 + w * 64;   // wave's 64 rows
    const int cbA = rowstart >> 5;                    // A col-blocks: cbA, cbA+1
    const int cb0 = blockIdx.x * 16;                  // 16 B col-blocks (512 cols)

    // --- A: two 32-row tiles, full K, 128 VGPRs, coalesced 1KB loads ---
    bf16x8 a0[16], a1[16];
    #pragma unroll
    for (int s = 0; s < 16; ++s) {
        a0[s] = *(const bf16x8*)(qn + (size_t)(s * 256 + cbA    ) * 512 + lane * 8);
        a1[s] = *(const bf16x8*)(qn + (size_t)(s * 256 + cbA + 1) * 512 + lane * 8);
    }

    const unsigned short* bbase = pn + lane * 8;
    // flat fragment index f: chunk c = f>>4, kstep s = f&15
    #define FRAG(f) (*(const bf16x8*)(bbase + \
        (size_t)((((f) & 15) * 256) + cb0 + ((f) >> 4)) * 512))

    bf16x8 bq[4] = { FRAG(0), FRAG(1), FRAG(2), FRAG(3) };

    f32x16 lsum0 = (f32x16)0.0f, lsum1 = (f32x16)0.0f;

    for (int c = 0; c < 16; ++c) {
        f32x16 acc0 = (f32x16)0.0f, acc1 = (f32x16)0.0f;
        #pragma unroll
        for (int s = 0; s < 16; ++s) {
            bf16x8 cur = bq[s & 3];
            const int f = c * 16 + s + 4;
            if (f < 256) bq[s & 3] = FRAG(f);     // rolling prefetch, dist 4
            acc0 = __builtin_amdgcn_mfma_f32_32x32x16_bf16(a0[s], cur, acc0, 0, 0, 0);
            acc1 = __builtin_amdgcn_mfma_f32_32x32x16_bf16(a1[s], cur, acc1, 0, 0, 0);
        }
        // per-chunk epilogue: accumulate exp into per-lane row partials
        #pragma unroll
        for (int r = 0; r < 16; ++r) {
            lsum0[r] += __expf(acc0[r] * INV_TEMP);
            lsum1[r] += __expf(acc1[r] * INV_TEMP);
        }
    }
    #undef FRAG

    // --- reduce over the 32 col-lanes of each half; 1 atomicAdd per row ---
    #pragma unroll
    for (int r = 0; r < 16; ++r) {
        float v0 = lsum0[r], v1 = lsum1[r];
        #pragma unroll
        for (int m = 1; m < 32; m <<= 1) {
            v0 += __shfl_xor(v0, m);
            v1 += __shfl_xor(v1, m);
        }
        if ((lane & 31) == 0) {
            const int rl = (r & 3) + 8 * (r >> 2) + ((lane >> 5) << 2);
            atomicAdd(&lse[rowstart + rl],      v0);
            atomicAdd(&lse[rowstart + 32 + rl], v1);
        }
    }

    // --- completion: last block computes the final loss ---
    __threadfence();
    __syncthreads();
    if (tid == 0) {
        const unsigned int nblk = gridDim.x * gridDim.y;
        is_last = (atomicAdd(counter, 1u) == nblk - 1u);
    }
    __syncthreads();
    if (is_last) {
        __threadfence();
        float s = 0.0f;
        for (int i = tid; i < NROWS; i += 256) {
            float v = __hip_atomic_load(&lse[i], __ATOMIC_RELAXED,
                                        __HIP_MEMORY_SCOPE_AGENT);
            s += __logf(v) - diag[i];
        }
        #pragma unroll
        for (int m = 1; m < 64; m <<= 1) s += __shfl_xor(s, m);
        if (lane == 0) wsum[w] = s;
        __syncthreads();
        if (tid == 0)
            out[0] = (wsum[0] + wsum[1] + wsum[2] + wsum[3]) * (1.0f / NROWS);
    }
}

// ---------------------------------------------------------------------------
extern "C" void kernel_launch(void* const* d_in, const int* in_sizes, int n_in,
                              void* d_out, int out_size, void* d_ws, size_t ws_size,
                              hipStream_t stream)
{
    const float* q = (const float*)d_in[0];
    const float* p = (const float*)d_in[1];

    char* ws = (char*)d_ws;
    unsigned short* qn = (unsigned short*)ws;                          // 4 MB
    unsigned short* pn = (unsigned short*)(ws + (size_t)NROWS*DDIM*2); // 4 MB
    float* diag = (float*)(ws + 2 * (size_t)NROWS * DDIM * 2);         // 32 KB
    float* lse  = diag + NROWS;                                        // 32 KB
    unsigned int* counter = (unsigned int*)(lse + NROWS);              // 4 B

    norm_diag_kernel<<<NROWS / 4, 256, 0, stream>>>(q, p, qn, pn, diag, lse, counter);

    dim3 grid(16, 32);   // colgroups(512 cols) x rowblocks(256 rows) = 512 blocks
    simexp_kernel<<<grid, 256, 0, stream>>>(qn, pn, lse, diag, counter, (float*)d_out);
}